// Round 18
// baseline (524.358 us; speedup 1.0000x reference)
//
#include <hip/hip_runtime.h>
#include <hip/hip_bf16.h>

typedef __bf16 bf16x8 __attribute__((ext_vector_type(8)));
typedef __bf16 bf16x4 __attribute__((ext_vector_type(4)));
typedef float f32x4 __attribute__((ext_vector_type(4)));
typedef float f32x2 __attribute__((ext_vector_type(2)));

__device__ __forceinline__ f32x4 mfma16(bf16x8 a, bf16x8 b, f32x4 c) {
  return __builtin_amdgcn_mfma_f32_16x16x32_bf16(a, b, c, 0, 0, 0);
}

__device__ __forceinline__ bf16x8 cvt8(const float* f) {
  bf16x8 r;
#pragma unroll
  for (int i = 0; i < 8; ++i) r[i] = (__bf16)f[i];
  return r;
}

// lgkm-only barrier (proven numerically safe in rounds 16-17)
#define SYNC_LGKM() \
  asm volatile("s_waitcnt lgkmcnt(0)\n\ts_barrier" ::: "memory")

// ---- block reduction helper (blockDim.x == 256, 4 waves) ----
__device__ __forceinline__ void blockRed2(float& a, float& b, float* red) {
#pragma unroll
  for (int off = 1; off < 64; off <<= 1) {
    a += __shfl_xor(a, off, 64);
    b += __shfl_xor(b, off, 64);
  }
  const int w = threadIdx.x >> 6;
  if ((threadIdx.x & 63) == 0) { red[w] = a; red[4 + w] = b; }
  __syncthreads();
  a = red[0] + red[1] + red[2] + red[3];
  b = red[4] + red[5] + red[6] + red[7];
  __syncthreads();
}

#define IMG_K 37632
#define SPLITK 49
#define STEPS_PER 24

// =====================================================================
// img body (proven 83us config)
// =====================================================================
__device__ __forceinline__ void img_body(
    int orig, const float* __restrict__ A, const float* __restrict__ B,
    __bf16* __restrict__ partials, __bf16 (*As)[5120], __bf16 (*Bs)[5120]) {
  const int t = threadIdx.x;
  const int lane = t & 63;
  const int w = t >> 6;
  const int wr = (w >> 2) * 64;
  const int wc = (w & 3) * 32;
  const int swz = (orig & 7) * 98 + (orig >> 3);
  const int m0 = ((swz >> 2) & 3) * 128;
  const int n0 = (swz & 3) * 128;
  const int zz = swz >> 4;
  const int step0 = zz * STEPS_PER;

  f32x4 acc[4][2];
#pragma unroll
  for (int i = 0; i < 4; ++i)
#pragma unroll
    for (int j = 0; j < 2; ++j) acc[i][j] = f32x4{0.f, 0.f, 0.f, 0.f};

  const int ar = t >> 2, ak = (t & 3) * 8;
  const int bn = t & 127, bk = (t >> 7) * 8;
  const int fr = lane & 15, fk = (lane >> 4) * 8;

  float r0a[8], r0b[8], r1a[8], r1b[8], r2a[8], r2b[8];
#define IMG_LOAD(AT, BT, K0)                                                \
  do {                                                                      \
    const float* asrc = A + (size_t)(m0 + ar) * IMG_K + (K0) + ak;          \
    f32x4 v0 = *reinterpret_cast<const f32x4*>(asrc);                       \
    f32x4 v1 = *reinterpret_cast<const f32x4*>(asrc + 4);                   \
    AT[0] = v0[0]; AT[1] = v0[1]; AT[2] = v0[2]; AT[3] = v0[3];             \
    AT[4] = v1[0]; AT[5] = v1[1]; AT[6] = v1[2]; AT[7] = v1[3];             \
    const float* bsrc = B + (size_t)((K0) + bk) * 512 + n0 + bn;            \
    _Pragma("unroll") for (int j = 0; j < 8; ++j) BT[j] =                   \
        bsrc[(size_t)j * 512];                                              \
  } while (0)
#define IMG_WRITE(BUF, AT, BT)                                              \
  do {                                                                      \
    *reinterpret_cast<bf16x8*>(&As[BUF][ar * 40 + ak]) = cvt8(AT);          \
    *reinterpret_cast<bf16x8*>(&Bs[BUF][bn * 40 + bk]) = cvt8(BT);          \
  } while (0)
#define IMG_MFMA(BUF)                                                       \
  do {                                                                      \
    bf16x8 af[4], bfr[2];                                                   \
    _Pragma("unroll") for (int i = 0; i < 4; ++i) af[i] =                   \
        *reinterpret_cast<const bf16x8*>(                                   \
            &As[BUF][(wr + i * 16 + fr) * 40 + fk]);                        \
    _Pragma("unroll") for (int j = 0; j < 2; ++j) bfr[j] =                  \
        *reinterpret_cast<const bf16x8*>(                                   \
            &Bs[BUF][(wc + j * 16 + fr) * 40 + fk]);                        \
    _Pragma("unroll") for (int i = 0; i < 4; ++i)                           \
        _Pragma("unroll") for (int j = 0; j < 2; ++j) acc[i][j] =           \
            mfma16(af[i], bfr[j], acc[i][j]);                               \
  } while (0)
#define IMG_STEP(S, BUF, WBUF, LA, LB, WA, WB)                              \
  do {                                                                      \
    if ((S) + 3 < STEPS_PER) IMG_LOAD(LA, LB, (step0 + (S) + 3) * 32);      \
    IMG_MFMA(BUF);                                                          \
    if ((S) + 1 < STEPS_PER) IMG_WRITE(WBUF, WA, WB);                       \
    SYNC_LGKM();                                                            \
  } while (0)

  IMG_LOAD(r0a, r0b, step0 * 32);
  IMG_WRITE(0, r0a, r0b);
  IMG_LOAD(r1a, r1b, (step0 + 1) * 32);
  IMG_LOAD(r2a, r2b, (step0 + 2) * 32);
  SYNC_LGKM();

  for (int s6 = 0; s6 < STEPS_PER; s6 += 6) {
    IMG_STEP(s6 + 0, 0, 1, r0a, r0b, r1a, r1b);
    IMG_STEP(s6 + 1, 1, 0, r1a, r1b, r2a, r2b);
    IMG_STEP(s6 + 2, 0, 1, r2a, r2b, r0a, r0b);
    IMG_STEP(s6 + 3, 1, 0, r0a, r0b, r1a, r1b);
    IMG_STEP(s6 + 4, 0, 1, r1a, r1b, r2a, r2b);
    IMG_STEP(s6 + 5, 1, 0, r2a, r2b, r0a, r0b);
  }
#undef IMG_LOAD
#undef IMG_WRITE
#undef IMG_MFMA
#undef IMG_STEP

  __bf16* P = partials + (size_t)zz * (512 * 512);
  const int rq = (lane >> 4) * 4;
#pragma unroll
  for (int i = 0; i < 4; ++i)
#pragma unroll
    for (int j = 0; j < 2; ++j)
#pragma unroll
      for (int r = 0; r < 4; ++r)
        P[(size_t)(m0 + wr + i * 16 + rq + r) * 512 + (n0 + wc + j * 16 + fr)] =
            (__bf16)acc[i][j][r];
}

// =====================================================================
// pool body (round-16 proven, LDS-staged A rows)
// =====================================================================
__device__ __forceinline__ void pool_body(
    int pbid, const float* __restrict__ qgrids, const int* __restrict__ lens,
    const __bf16* __restrict__ Wt, const float* __restrict__ bias,
    const float* __restrict__ g, const float* __restrict__ bt,
    __bf16* __restrict__ pooled, float (*red)[16][2], float (*Arows)[258]) {
  const int t = threadIdx.x, lane = t & 63, w = t >> 6;
  const int b = pbid >> 5;
  const int j0 = (pbid & 31) * 16;
  const int L = lens[b];
  int S = (L + 511) >> 9;
  if (S < 1) S = 1;
  const int new_len = (L + S - 1) / S;
  const float* qg_b = qgrids + (size_t)b * 4096 * 242;
  __bf16* pooled_b = pooled + (size_t)b * 512 * 512;

  const int fr = lane & 15;
  const int fq = lane >> 4;
  const int fkq = fq * 8;
  const int colbase = w * 64;

  float biasv[4], gv[4], btv[4];
#pragma unroll
  for (int nt = 0; nt < 4; ++nt) {
    const int col = colbase + nt * 16 + fr;
    biasv[nt] = bias[col];
    gv[nt] = g[col];
    btv[nt] = bt[col];
  }

  f32x4 pool[4];
#pragma unroll
  for (int nt = 0; nt < 4; ++nt) pool[nt] = f32x4{0.f, 0.f, 0.f, 0.f};

  {
    const int row = t >> 5, l32 = t & 31;
    if (l32 < 16) Arows[row][242 + l32] = 0.f;
  }

  for (int i = 0; i < S; ++i) {
    {
      const int row = t >> 5, l32 = t & 31;
      const int arow = (j0 + row) * S + i;
      const float* src = qg_b + (size_t)arow * 242;
#pragma unroll
      for (int c8 = 0; c8 < 4; ++c8) {
        const int c = (l32 + c8 * 32) * 2;
        if (c < 242) {
          f32x2 v = *reinterpret_cast<const f32x2*>(src + c);
          Arows[row][c] = v[0];
          Arows[row][c + 1] = v[1];
        }
      }
    }
    __syncthreads();
    f32x4 acc[4];
#pragma unroll
    for (int nt = 0; nt < 4; ++nt) acc[nt] = f32x4{0.f, 0.f, 0.f, 0.f};
#pragma unroll
    for (int ks = 0; ks < 8; ++ks) {
      bf16x8 af = cvt8(&Arows[fr][ks * 32 + fkq]);
      const __bf16* wt = Wt + ks * 32 + fkq;
#pragma unroll
      for (int nt = 0; nt < 4; ++nt) {
        bf16x8 bfv = *reinterpret_cast<const bf16x8*>(
            wt + (size_t)(colbase + nt * 16 + fr) * 256);
        acc[nt] = mfma16(af, bfv, acc[nt]);
      }
    }
    float s[4] = {0.f, 0.f, 0.f, 0.f}, sq[4] = {0.f, 0.f, 0.f, 0.f};
#pragma unroll
    for (int nt = 0; nt < 4; ++nt) {
#pragma unroll
      for (int r = 0; r < 4; ++r) {
        const float v = acc[nt][r] + biasv[nt];
        acc[nt][r] = v;
        s[r] += v;
        sq[r] += v * v;
      }
    }
#pragma unroll
    for (int off = 1; off < 16; off <<= 1) {
#pragma unroll
      for (int r = 0; r < 4; ++r) {
        s[r] += __shfl_xor(s[r], off, 64);
        sq[r] += __shfl_xor(sq[r], off, 64);
      }
    }
    if (fr == 0) {
#pragma unroll
      for (int r = 0; r < 4; ++r) {
        red[w][fq * 4 + r][0] = s[r];
        red[w][fq * 4 + r][1] = sq[r];
      }
    }
    __syncthreads();
    float mean[4], rsig[4];
#pragma unroll
    for (int r = 0; r < 4; ++r) {
      const int p = fq * 4 + r;
      float ss = 0.f, qq = 0.f;
#pragma unroll
      for (int ww = 0; ww < 8; ++ww) {
        ss += red[ww][p][0];
        qq += red[ww][p][1];
      }
      const float m = ss * (1.f / 512.f);
      mean[r] = m;
      rsig[r] = rsqrtf(qq * (1.f / 512.f) - m * m + 1e-5f);
    }
    __syncthreads();
#pragma unroll
    for (int r = 0; r < 4; ++r) {
      const int srow = (j0 + fq * 4 + r) * S + i;
      const bool ok = srow < L;
#pragma unroll
      for (int nt = 0; nt < 4; ++nt) {
        const float nv = (acc[nt][r] - mean[r]) * rsig[r] * gv[nt] + btv[nt];
        pool[nt][r] += ok ? nv : 0.f;
      }
    }
  }
  const float inv = 1.f / (float)S;
#pragma unroll
  for (int r = 0; r < 4; ++r) {
    const int j = j0 + fq * 4 + r;
    const bool ok = j < new_len;
#pragma unroll
    for (int nt = 0; nt < 4; ++nt)
      pooled_b[(size_t)j * 512 + colbase + nt * 16 + fr] =
          (__bf16)(ok ? pool[nt][r] * inv : 0.f);
  }
}

// kp body (512-thread mapping)
__device__ __forceinline__ void kp_body(
    int kpbid, const __bf16* __restrict__ A, const __bf16* __restrict__ Wt,
    const float* __restrict__ bias, float* __restrict__ C) {
  const int t = threadIdx.x, lane = t & 63, w = t >> 6;
  const int n0 = (kpbid & 31) * 16;
  const int m0 = (kpbid >> 5) * 128 + w * 16;
  const int fr = lane & 15, fq = lane >> 4;
  const __bf16* arow = A + (size_t)(m0 + fr) * 256 + fq * 8;
  const __bf16* brow = Wt + (size_t)(n0 + fr) * 256 + fq * 8;
  f32x4 acc = f32x4{0.f, 0.f, 0.f, 0.f};
#pragma unroll
  for (int ks = 0; ks < 8; ++ks) {
    bf16x8 a = *reinterpret_cast<const bf16x8*>(arow + ks * 32);
    bf16x8 b = *reinterpret_cast<const bf16x8*>(brow + ks * 32);
    acc = mfma16(a, b, acc);
  }
  const int col = n0 + fr;
  const float bv = bias[col];
  const int r0 = m0 + fq * 4;
#pragma unroll
  for (int r = 0; r < 4; ++r)
    C[(size_t)(r0 + r) * 512 + col] = fmaxf(acc[r] + bv, 0.f);
}

// =====================================================================
// Phase-1 fused: pool (bid<256) | img (bid<1040) | kp (else).
// __launch_bounds__(512, 6) caps VGPR at ~85: the round-17 union
// allocated 128 VGPR, halving img occupancy (21%). img needs only 60.
// Tripwire: if WRITE_SIZE >> 30 MB next profile, pool spilled -> revert.
// =====================================================================
__global__ __launch_bounds__(512, 6) void phase1_kernel(
    const float* __restrict__ images, const float* __restrict__ W_img,
    __bf16* __restrict__ partials, const float* __restrict__ qgrids,
    const int* __restrict__ lens, const __bf16* __restrict__ wtq,
    const float* __restrict__ b_qp, const float* __restrict__ g_qln,
    const float* __restrict__ bt_qln, __bf16* __restrict__ pooled,
    const __bf16* __restrict__ kpbf, const __bf16* __restrict__ wkp_t,
    const float* __restrict__ b_kp, float* __restrict__ kptmp) {
  __shared__ union {
    struct {
      __bf16 As[2][5120];
      __bf16 Bs[2][5120];
    } img;
    struct {
      float red[8][16][2];
      float Arows[16][258];
    } pool;
  } sm;
  const int bid = blockIdx.x;
  if (bid < 256) {
    pool_body(bid, qgrids, lens, wtq, b_qp, g_qln, bt_qln, pooled,
              sm.pool.red, sm.pool.Arows);
  } else if (bid < 1040) {
    img_body(bid - 256, images, W_img, partials, sm.img.As, sm.img.Bs);
  } else {
    kp_body(bid - 1040, kpbf, wkp_t, b_kp, kptmp);
  }
}

// =====================================================================
// reduce_ln: fusedbf[row, :512] = bf16( LN(kptmp[row])*g+bt + b_img
//                                       + sum_z partials[z][row] )
// =====================================================================
__global__ __launch_bounds__(256) void reduce_ln_kernel(
    const float* __restrict__ kptmp, const float* __restrict__ g,
    const float* __restrict__ bt, const __bf16* __restrict__ partials,
    const float* __restrict__ b_img, __bf16* __restrict__ fusedbf) {
  __shared__ float red[8];
  const int t = threadIdx.x;
  const int row = blockIdx.x;
  const size_t off = (size_t)row * 512;
  const float a = kptmp[off + t], b2 = kptmp[off + t + 256];
  float s = a + b2, sq = a * a + b2 * b2;
  blockRed2(s, sq, red);
  const float m = s * (1.f / 512.f);
  const float var = sq * (1.f / 512.f) - m * m;
  const float rs = rsqrtf(var + 1e-5f);
  float acc0 = (a - m) * rs * g[t] + bt[t] + b_img[t];
  float acc1 = (b2 - m) * rs * g[t + 256] + bt[t + 256] + b_img[t + 256];
#pragma unroll
  for (int z = 0; z < SPLITK; ++z) {
    acc0 += (float)partials[(size_t)z * 262144 + off + t];
    acc1 += (float)partials[(size_t)z * 262144 + off + t + 256];
  }
  __bf16* dst = fusedbf + (size_t)row * 1024;
  dst[t] = (__bf16)acc0;
  dst[t + 256] = (__bf16)acc1;
}

// =====================================================================
// transpose body (LDS-tiled): W [NK][NC] f32 -> Wt [NC][NK]
// =====================================================================
__device__ __forceinline__ void wtrans_body(const float* __restrict__ W,
                                            __bf16* __restrict__ Wt, int NC,
                                            int NK, int bx, int by) {
  __shared__ float T[32][33];
  const int t = threadIdx.x;
  const int c0 = bx * 32;
  const int k0 = by * 32;
#pragma unroll
  for (int r = 0; r < 4; ++r) {
    const int idx = r * 256 + t;
    const int i = idx >> 5, j = idx & 31;
    const int c = c0 + j;
    T[i][j] = (c < NC) ? W[(size_t)(k0 + i) * NC + c] : 0.f;
  }
  __syncthreads();
#pragma unroll
  for (int r = 0; r < 4; ++r) {
    const int idx = r * 256 + t;
    const int i = idx >> 5, j = idx & 31;
    const int c = c0 + i;
    if (c < NC) Wt[(size_t)c * NK + k0 + j] = (__bf16)T[j][i];
  }
}

// =====================================================================
// Phase-0 fused prep: prep3 (bid<1536) | qkvo transposes (else, 1024)
// =====================================================================
__global__ __launch_bounds__(256) void phase0_kernel(
    const float* __restrict__ W_qp, __bf16* __restrict__ wtq,
    const float* __restrict__ W_kp, __bf16* __restrict__ wkp_t,
    const float* __restrict__ kp, __bf16* __restrict__ kpbf,
    const float* __restrict__ Wq, const float* __restrict__ Wk,
    const float* __restrict__ Wv, const float* __restrict__ Wo,
    __bf16* __restrict__ wq_t, __bf16* __restrict__ wk_t,
    __bf16* __restrict__ wv_t, __bf16* __restrict__ wo_t) {
  const int bid = blockIdx.x;
  const int t = threadIdx.x;
  if (bid < 512) {
    wtq[(size_t)bid * 256 + t] =
        (t < 242) ? (__bf16)W_qp[(size_t)t * 512 + bid] : (__bf16)0.f;
  } else if (bid < 1024) {
    const int c = bid - 512;
    wkp_t[(size_t)c * 256 + t] =
        (t < 242) ? (__bf16)W_kp[(size_t)t * 512 + c] : (__bf16)0.f;
  } else if (bid < 1536) {
    const int r = bid - 1024;
    kpbf[(size_t)r * 256 + t] =
        (t < 242) ? (__bf16)kp[(size_t)r * 242 + t] : (__bf16)0.f;
  } else {
    const int idx = bid - 1536;
    const int z = idx >> 8, rem = idx & 255;
    const float* W = (z == 0) ? Wq : (z == 1) ? Wk : (z == 2) ? Wv : Wo;
    __bf16* Wt = (z == 0) ? wq_t : (z == 1) ? wk_t : (z == 2) ? wv_t : wo_t;
    wtrans_body(W, Wt, 512, 512, rem & 15, rem >> 4);
  }
}

// =====================================================================
// Phase-3 fused (all independent after reduce_ln; partials dead):
//   bid < 4096: k/v reg GEMM  (z=bid>>11, n0/m0 from low bits)
//   bid < 4352: q reg GEMM    (A = fusedbf low half, lda=1024)
//   else      : W_ctc transpose (1312 blocks)
// =====================================================================
__global__ __launch_bounds__(256) void phase3_kernel(
    const __bf16* __restrict__ pooled, const __bf16* __restrict__ wk_t,
    const float* __restrict__ bk, const __bf16* __restrict__ wv_t,
    const float* __restrict__ bv, __bf16* __restrict__ kout,
    __bf16* __restrict__ vout, const __bf16* __restrict__ fusedbf,
    const __bf16* __restrict__ wq_t, const float* __restrict__ bq,
    __bf16* __restrict__ qout, const float* __restrict__ W_ctc,
    __bf16* __restrict__ wtc) {
  const int bid = blockIdx.x;
  const int t = threadIdx.x, lane = t & 63, w = t >> 6;
  const int fr = lane & 15, fq = lane >> 4;
  if (bid < 4352) {
    const __bf16* A;
    const __bf16* Wt;
    const float* bias;
    __bf16* C;
    int lda, n0, m0;
    if (bid < 4096) {
      const int z = bid >> 11, r2 = bid & 2047;
      A = pooled;
      lda = 512;
      Wt = z ? wv_t : wk_t;
      bias = z ? bv : bk;
      C = z ? vout : kout;
      n0 = (r2 & 31) * 16;
      m0 = (r2 >> 5) * 64 + w * 16;
    } else {
      const int qi = bid - 4096;
      A = fusedbf;
      lda = 1024;
      Wt = wq_t;
      bias = bq;
      C = qout;
      n0 = (qi & 31) * 16;
      m0 = (qi >> 5) * 64 + w * 16;
    }
    const __bf16* arow = A + (size_t)(m0 + fr) * lda + fq * 8;
    const __bf16* brow = Wt + (size_t)(n0 + fr) * 512 + fq * 8;
    f32x4 acc = f32x4{0.f, 0.f, 0.f, 0.f};
#pragma unroll
    for (int ks = 0; ks < 16; ++ks) {
      bf16x8 a = *reinterpret_cast<const bf16x8*>(arow + ks * 32);
      bf16x8 b = *reinterpret_cast<const bf16x8*>(brow + ks * 32);
      acc = mfma16(a, b, acc);
    }
    const int col = n0 + fr;
    const float bvv = bias[col];
    const int r0 = m0 + fq * 4;
#pragma unroll
    for (int r = 0; r < 4; ++r)
      C[(size_t)(r0 + r) * 512 + col] = (__bf16)(acc[r] + bvv);
  } else {
    const int wi = bid - 4352;
    wtrans_body(W_ctc, wtc, 1296, 1024, wi % 41, wi / 41);
  }
}

// CTC head register GEMM (K=1024)
__global__ __launch_bounds__(256) void ctc_gemm_kernel(
    const __bf16* __restrict__ A, const __bf16* __restrict__ Wt,
    const float* __restrict__ bias, float* __restrict__ out) {
  const int t = threadIdx.x, lane = t & 63, w = t >> 6;
  const int n0 = blockIdx.x * 16;
  const int m0 = blockIdx.y * 64 + w * 16;
  const int fr = lane & 15, fq = lane >> 4;
  const __bf16* arow = A + (size_t)(m0 + fr) * 1024 + fq * 8;
  const __bf16* brow = Wt + (size_t)(n0 + fr) * 1024 + fq * 8;
  f32x4 acc = f32x4{0.f, 0.f, 0.f, 0.f};
#pragma unroll
  for (int ks = 0; ks < 32; ++ks) {
    bf16x8 a = *reinterpret_cast<const bf16x8*>(arow + ks * 32);
    bf16x8 b = *reinterpret_cast<const bf16x8*>(brow + ks * 32);
    acc = mfma16(a, b, acc);
  }
  const int col = n0 + fr;
  const float bv = bias[col];
  const int r0 = m0 + fq * 4;
#pragma unroll
  for (int r = 0; r < 4; ++r)
    out[(size_t)(r0 + r) * 1296 + col] = acc[r] + bv;
}

// wo register GEMM (K=512, f32 out)
__global__ __launch_bounds__(256) void wo_gemm_kernel(
    const __bf16* __restrict__ A, const __bf16* __restrict__ Wt,
    const float* __restrict__ bias, float* __restrict__ C) {
  const int t = threadIdx.x, lane = t & 63, w = t >> 6;
  const int n0 = blockIdx.x * 16;
  const int m0 = blockIdx.y * 64 + w * 16;
  const int fr = lane & 15, fq = lane >> 4;
  const __bf16* arow = A + (size_t)(m0 + fr) * 512 + fq * 8;
  const __bf16* brow = Wt + (size_t)(n0 + fr) * 512 + fq * 8;
  f32x4 acc = f32x4{0.f, 0.f, 0.f, 0.f};
#pragma unroll
  for (int ks = 0; ks < 16; ++ks) {
    bf16x8 a = *reinterpret_cast<const bf16x8*>(arow + ks * 32);
    bf16x8 b = *reinterpret_cast<const bf16x8*>(brow + ks * 32);
    acc = mfma16(a, b, acc);
  }
  const int col = n0 + fr;
  const float bv = bias[col];
  const int r0 = m0 + fq * 4;
#pragma unroll
  for (int r = 0; r < 4; ++r)
    C[(size_t)(r0 + r) * 512 + col] = acc[r] + bv;
}

// =====================================================================
// Fused attention (unchanged, proven)
// =====================================================================
__global__ __launch_bounds__(256) void attn_fused_kernel(
    const __bf16* __restrict__ q, const __bf16* __restrict__ k,
    const __bf16* __restrict__ v, const int* __restrict__ lens,
    __bf16* __restrict__ ctx) {
  __shared__ __bf16 Qs[64 * 72];
  __shared__ __bf16 Ps[64 * 520];
  __shared__ __bf16 KVs[64 * 520];
  const int t = threadIdx.x, lane = t & 63, w = t >> 6;
  const int bh = blockIdx.x, b = bh >> 3, h = bh & 7;
  const int L = lens[b];
  const int sdiv = (L + 511) >> 9;
  const int new_len = (L + sdiv - 1) / sdiv;
  const size_t qbase = (size_t)b * 64 * 512 + h * 64;
  const size_t kbase = (size_t)b * 512 * 512 + h * 64;
  const size_t vbase = kbase;
  const int fr = lane & 15, fkq = (lane >> 4) * 8;

#pragma unroll
  for (int rep = 0; rep < 4; ++rep) {
    const int gidx = rep * 256 + t;
    const int row = gidx >> 4, c = (gidx & 15) * 4;
    *reinterpret_cast<bf16x4*>(&Qs[row * 72 + c]) =
        *reinterpret_cast<const bf16x4*>(&q[qbase + (size_t)row * 512 + c]);
  }
  f32x4 acc[32];
#pragma unroll
  for (int nt = 0; nt < 32; ++nt) acc[nt] = f32x4{0.f, 0.f, 0.f, 0.f};
  for (int ks = 0; ks < 2; ++ks) {
    const int k0 = ks * 32;
#pragma unroll
    for (int rep = 0; rep < 16; ++rep) {
      const int gidx = rep * 256 + t;
      const int row = gidx >> 3, c = (gidx & 7) * 4;
      *reinterpret_cast<bf16x4*>(&KVs[row * 40 + c]) =
          *reinterpret_cast<const bf16x4*>(&k[kbase + (size_t)row * 512 + k0 + c]);
    }
    __syncthreads();
    const bf16x8 af =
        *reinterpret_cast<const bf16x8*>(&Qs[(w * 16 + fr) * 72 + k0 + fkq]);
#pragma unroll
    for (int nt = 0; nt < 32; ++nt) {
      bf16x8 bf = *reinterpret_cast<const bf16x8*>(&KVs[(nt * 16 + fr) * 40 + fkq]);
      acc[nt] = mfma16(af, bf, acc[nt]);
    }
    __syncthreads();
  }
  const float scale = 0.125f;
#pragma unroll
  for (int r = 0; r < 4; ++r) {
    float mx = -3.0e38f;
#pragma unroll
    for (int nt = 0; nt < 32; ++nt) {
      const int col = nt * 16 + fr;
      const float sv = acc[nt][r] * scale;
      if (col < new_len) mx = fmaxf(mx, sv);
    }
#pragma unroll
    for (int off = 1; off < 16; off <<= 1) mx = fmaxf(mx, __shfl_xor(mx, off, 64));
    float sum = 0.f;
#pragma unroll
    for (int nt = 0; nt < 32; ++nt) {
      const int col = nt * 16 + fr;
      const float e = (col < new_len) ? __expf(acc[nt][r] * scale - mx) : 0.f;
      acc[nt][r] = e;
      sum += e;
    }
#pragma unroll
    for (int off = 1; off < 16; off <<= 1) sum += __shfl_xor(sum, off, 64);
    const float inv = 1.f / sum;
    const int row = w * 16 + ((lane >> 4) << 2) + r;
#pragma unroll
    for (int nt = 0; nt < 32; ++nt)
      Ps[row * 520 + nt * 16 + fr] = (__bf16)(acc[nt][r] * inv);
  }
  __syncthreads();
  {
    const int d = t & 63;
    const int kc = (t >> 6) * 128;
    const int sw = (d & 7) << 3;
#pragma unroll
    for (int j8 = 0; j8 < 16; ++j8) {
      const int kv0 = kc + j8 * 8;
      bf16x8 tmp;
#pragma unroll
      for (int jj = 0; jj < 8; ++jj)
        tmp[jj] = v[vbase + (size_t)(kv0 + jj) * 512 + d];
      *reinterpret_cast<bf16x8*>(&KVs[d * 520 + (kv0 ^ sw)]) = tmp;
    }
  }
  __syncthreads();
  f32x4 acc2[4];
#pragma unroll
  for (int nt = 0; nt < 4; ++nt) acc2[nt] = f32x4{0.f, 0.f, 0.f, 0.f};
  const int swr = (fr & 7) << 3;
#pragma unroll
  for (int s = 0; s < 16; ++s) {
    const int k0 = s * 32;
    const bf16x8 af =
        *reinterpret_cast<const bf16x8*>(&Ps[(w * 16 + fr) * 520 + k0 + fkq]);
#pragma unroll
    for (int nt = 0; nt < 4; ++nt) {
      bf16x8 bf = *reinterpret_cast<const bf16x8*>(
          &KVs[(nt * 16 + fr) * 520 + ((k0 + fkq) ^ swr)]);
      acc2[nt] = mfma16(af, bf, acc2[nt]);
    }
  }
  const int rq = (lane >> 4) * 4;
  const size_t cbase = (size_t)b * 64 * 512 + h * 64;
#pragma unroll
  for (int nt = 0; nt < 4; ++nt)
#pragma unroll
    for (int r = 0; r < 4; ++r)
      ctx[cbase + (size_t)(w * 16 + rq + r) * 512 + nt * 16 + fr] =
          (__bf16)acc2[nt][r];
}

// LayerNorm over rows of 512, bf16 output into fusedbf[:, 512:1024]
__global__ __launch_bounds__(256) void ln_bf16_kernel(
    const float* __restrict__ x, const float* __restrict__ g,
    const float* __restrict__ bt, __bf16* __restrict__ ybf) {
  __shared__ float red[8];
  const int t = threadIdx.x;
  const size_t off = (size_t)blockIdx.x * 512;
  const float a = x[off + t], b2 = x[off + t + 256];
  float s = a + b2, sq = a * a + b2 * b2;
  blockRed2(s, sq, red);
  const float m = s * (1.f / 512.f);
  const float var = sq * (1.f / 512.f) - m * m;
  const float rs = rsqrtf(var + 1e-5f);
  __bf16* yrow = ybf + (size_t)blockIdx.x * 1024;
  yrow[t] = (__bf16)((a - m) * rs * g[t] + bt[t]);
  yrow[t + 256] = (__bf16)((b2 - m) * rs * g[t + 256] + bt[t + 256]);
}

// =====================================================================
// Workspace layout (audited for phase-1/phase-3 concurrency):
//   ws+ 0.. 1    kptmp f32 (phase1 -> reduce_ln)
//   ws+ 1..1.5   qbuf bf16 (phase3 -> attn)
//   ws+1.5..2    ctxbf bf16 (attn -> wo)
//   ws+ 2.. 3    wtq 256KB (phase0 -> phase1) / ctxo f32 (wo -> ln)
//   ws+ 3.. 4    fusedbf (reduce_ln -> phase3/ctc; ln -> ctc)
//   ws+ 4.. 8    pooled bf16 (phase1 -> phase3)  [exclusive]
//   ws+ 8..32.5  partials (phase1 -> reduce_ln); after death:
//                kbuf 8..12, vbuf 12..16, wtc 16..18.6 (phase3 writes,
//                disjoint from each other; partials dead by then)
//   ws+32.5..34.5 wq_t/wk_t/wv_t/wo_t
//   ws+34.5..34.75 kpbf; 34.75..35 wkp_t
// =====================================================================
extern "C" void kernel_launch(void* const* d_in, const int* in_sizes, int n_in,
                              void* d_out, int out_size, void* d_ws,
                              size_t ws_size, hipStream_t stream) {
  const float* images = (const float*)d_in[0];
  const float* qgrids = (const float*)d_in[1];
  const float* keypoints = (const float*)d_in[2];
  const int* qlens = (const int*)d_in[3];
  const float* W_img = (const float*)d_in[4];
  const float* b_img = (const float*)d_in[5];
  const float* W_kp = (const float*)d_in[6];
  const float* b_kp = (const float*)d_in[7];
  const float* g_kp = (const float*)d_in[8];
  const float* bt_kp = (const float*)d_in[9];
  const float* W_qp = (const float*)d_in[10];
  const float* b_qp = (const float*)d_in[11];
  const float* g_qln = (const float*)d_in[12];
  const float* bt_qln = (const float*)d_in[13];
  const float* Wq = (const float*)d_in[14];
  const float* bq = (const float*)d_in[15];
  const float* Wk = (const float*)d_in[16];
  const float* bk = (const float*)d_in[17];
  const float* Wv = (const float*)d_in[18];
  const float* bv = (const float*)d_in[19];
  const float* Wo = (const float*)d_in[20];
  const float* bo = (const float*)d_in[21];
  const float* g_attn = (const float*)d_in[22];
  const float* bt_attn = (const float*)d_in[23];
  const float* W_ctc = (const float*)d_in[24];
  const float* b_ctc = (const float*)d_in[25];
  float* out = (float*)d_out;

  const size_t MB = 1u << 20;
  const size_t KB = 1u << 10;
  if (ws_size < 35 * MB) return;
  char* ws = (char*)d_ws;
  float* kptmp = (float*)(ws);
  __bf16* qbuf = (__bf16*)(ws + 1 * MB);
  __bf16* ctxbf = (__bf16*)(ws + 1 * MB + 512 * KB);
  __bf16* wtq = (__bf16*)(ws + 2 * MB);
  float* ctxo = (float*)(ws + 2 * MB);
  __bf16* fusedbf = (__bf16*)(ws + 3 * MB);
  __bf16* pooled = (__bf16*)(ws + 4 * MB);
  __bf16* partials = (__bf16*)(ws + 8 * MB);
  __bf16* kbuf = (__bf16*)(ws + 8 * MB);    // after partials die
  __bf16* vbuf = (__bf16*)(ws + 12 * MB);   // after partials die
  __bf16* wtc = (__bf16*)(ws + 16 * MB);    // after partials die
  __bf16* wq_t = (__bf16*)(ws + 32 * MB + 512 * KB);
  __bf16* wk_t = (__bf16*)(ws + 33 * MB);
  __bf16* wv_t = (__bf16*)(ws + 33 * MB + 512 * KB);
  __bf16* wo_t = (__bf16*)(ws + 34 * MB);
  __bf16* kpbf = (__bf16*)(ws + 34 * MB + 512 * KB);
  __bf16* wkp_t = (__bf16*)(ws + 34 * MB + 768 * KB);

  // 0) prep: wqp^T | wkp^T | kp cast | qkvo transposes (one launch)
  phase0_kernel<<<2560, 256, 0, stream>>>(W_qp, wtq, W_kp, wkp_t, keypoints,
                                          kpbf, Wq, Wk, Wv, Wo, wq_t, wk_t,
                                          wv_t, wo_t);
  // 1) phase-1 fused: pool(256) | img(784) | kp(128), VGPR-capped
  phase1_kernel<<<1168, 512, 0, stream>>>(images, W_img, partials, qgrids,
                                          qlens, wtq, b_qp, g_qln, bt_qln,
                                          pooled, kpbf, wkp_t, b_kp, kptmp);
  // 2) reduce_ln: LN(kptmp) + b_img + sum(partials) -> fusedbf[:, :512]
  reduce_ln_kernel<<<512, 256, 0, stream>>>(kptmp, g_kp, bt_kp, partials,
                                            b_img, fusedbf);
  // 3) phase-3 fused: kv(4096) | q(256) | wtc(1312)
  phase3_kernel<<<5664, 256, 0, stream>>>(pooled, wk_t, bk, wv_t, bv, kbuf,
                                          vbuf, fusedbf, wq_t, bq, qbuf,
                                          W_ctc, wtc);
  // 4) fused attention
  attn_fused_kernel<<<64, 256, 0, stream>>>(qbuf, kbuf, vbuf, qlens, ctxbf);
  // 5) ctx @ Wo + bo (f32), then LN -> fusedbf[:, 512:]
  wo_gemm_kernel<<<dim3(32, 8), 256, 0, stream>>>(ctxbf, wo_t, bo, ctxo);
  ln_bf16_kernel<<<512, 256, 0, stream>>>(ctxo, g_attn, bt_attn, fusedbf + 512);
  // 6) out = fusedbf @ Wt_ctc^T + b_ctc
  ctc_gemm_kernel<<<dim3(81, 8), 256, 0, stream>>>(fusedbf, wtc, b_ctc, out);
}

// Round 19
// 203.823 us; speedup vs baseline: 2.5726x; 2.5726x over previous
//
#include <hip/hip_runtime.h>
#include <hip/hip_bf16.h>

typedef __bf16 bf16x8 __attribute__((ext_vector_type(8)));
typedef __bf16 bf16x4 __attribute__((ext_vector_type(4)));
typedef float f32x4 __attribute__((ext_vector_type(4)));
typedef float f32x2 __attribute__((ext_vector_type(2)));

__device__ __forceinline__ f32x4 mfma16(bf16x8 a, bf16x8 b, f32x4 c) {
  return __builtin_amdgcn_mfma_f32_16x16x32_bf16(a, b, c, 0, 0, 0);
}

__device__ __forceinline__ bf16x8 cvt8(const float* f) {
  bf16x8 r;
#pragma unroll
  for (int i = 0; i < 8; ++i) r[i] = (__bf16)f[i];
  return r;
}

// lgkm-only barrier (proven numerically safe rounds 16-18)
#define SYNC_LGKM() \
  asm volatile("s_waitcnt lgkmcnt(0)\n\ts_barrier" ::: "memory")

// ---- block reduction helper (blockDim.x == 256, 4 waves) ----
__device__ __forceinline__ void blockRed2(float& a, float& b, float* red) {
#pragma unroll
  for (int off = 1; off < 64; off <<= 1) {
    a += __shfl_xor(a, off, 64);
    b += __shfl_xor(b, off, 64);
  }
  const int w = threadIdx.x >> 6;
  if ((threadIdx.x & 63) == 0) { red[w] = a; red[4 + w] = b; }
  __syncthreads();
  a = red[0] + red[1] + red[2] + red[3];
  b = red[4] + red[5] + red[6] + red[7];
  __syncthreads();
}

#define IMG_K 37632
#define SPLITK 49
#define STEPS_PER 24

// =====================================================================
// img body (proven 83us config). NEEDS >=100 VGPR: any launch_bounds
// cap below that spills the reg pipeline catastrophically (rounds 11,18:
// WRITE_SIZE 25->685MB, 4x slowdown). Do NOT add min-waves bounds here.
// =====================================================================
__device__ __forceinline__ void img_body(
    int orig, const float* __restrict__ A, const float* __restrict__ B,
    __bf16* __restrict__ partials, __bf16 (*As)[5120], __bf16 (*Bs)[5120]) {
  const int t = threadIdx.x;
  const int lane = t & 63;
  const int w = t >> 6;
  const int wr = (w >> 2) * 64;
  const int wc = (w & 3) * 32;
  const int swz = (orig & 7) * 98 + (orig >> 3);
  const int m0 = ((swz >> 2) & 3) * 128;
  const int n0 = (swz & 3) * 128;
  const int zz = swz >> 4;
  const int step0 = zz * STEPS_PER;

  f32x4 acc[4][2];
#pragma unroll
  for (int i = 0; i < 4; ++i)
#pragma unroll
    for (int j = 0; j < 2; ++j) acc[i][j] = f32x4{0.f, 0.f, 0.f, 0.f};

  const int ar = t >> 2, ak = (t & 3) * 8;
  const int bn = t & 127, bk = (t >> 7) * 8;
  const int fr = lane & 15, fk = (lane >> 4) * 8;

  float r0a[8], r0b[8], r1a[8], r1b[8], r2a[8], r2b[8];
#define IMG_LOAD(AT, BT, K0)                                                \
  do {                                                                      \
    const float* asrc = A + (size_t)(m0 + ar) * IMG_K + (K0) + ak;          \
    f32x4 v0 = *reinterpret_cast<const f32x4*>(asrc);                       \
    f32x4 v1 = *reinterpret_cast<const f32x4*>(asrc + 4);                   \
    AT[0] = v0[0]; AT[1] = v0[1]; AT[2] = v0[2]; AT[3] = v0[3];             \
    AT[4] = v1[0]; AT[5] = v1[1]; AT[6] = v1[2]; AT[7] = v1[3];             \
    const float* bsrc = B + (size_t)((K0) + bk) * 512 + n0 + bn;            \
    _Pragma("unroll") for (int j = 0; j < 8; ++j) BT[j] =                   \
        bsrc[(size_t)j * 512];                                              \
  } while (0)
#define IMG_WRITE(BUF, AT, BT)                                              \
  do {                                                                      \
    *reinterpret_cast<bf16x8*>(&As[BUF][ar * 40 + ak]) = cvt8(AT);          \
    *reinterpret_cast<bf16x8*>(&Bs[BUF][bn * 40 + bk]) = cvt8(BT);          \
  } while (0)
#define IMG_MFMA(BUF)                                                       \
  do {                                                                      \
    bf16x8 af[4], bfr[2];                                                   \
    _Pragma("unroll") for (int i = 0; i < 4; ++i) af[i] =                   \
        *reinterpret_cast<const bf16x8*>(                                   \
            &As[BUF][(wr + i * 16 + fr) * 40 + fk]);                        \
    _Pragma("unroll") for (int j = 0; j < 2; ++j) bfr[j] =                  \
        *reinterpret_cast<const bf16x8*>(                                   \
            &Bs[BUF][(wc + j * 16 + fr) * 40 + fk]);                        \
    _Pragma("unroll") for (int i = 0; i < 4; ++i)                           \
        _Pragma("unroll") for (int j = 0; j < 2; ++j) acc[i][j] =           \
            mfma16(af[i], bfr[j], acc[i][j]);                               \
  } while (0)
#define IMG_STEP(S, BUF, WBUF, LA, LB, WA, WB)                              \
  do {                                                                      \
    if ((S) + 3 < STEPS_PER) IMG_LOAD(LA, LB, (step0 + (S) + 3) * 32);      \
    IMG_MFMA(BUF);                                                          \
    if ((S) + 1 < STEPS_PER) IMG_WRITE(WBUF, WA, WB);                       \
    SYNC_LGKM();                                                            \
  } while (0)

  IMG_LOAD(r0a, r0b, step0 * 32);
  IMG_WRITE(0, r0a, r0b);
  IMG_LOAD(r1a, r1b, (step0 + 1) * 32);
  IMG_LOAD(r2a, r2b, (step0 + 2) * 32);
  SYNC_LGKM();

  for (int s6 = 0; s6 < STEPS_PER; s6 += 6) {
    IMG_STEP(s6 + 0, 0, 1, r0a, r0b, r1a, r1b);
    IMG_STEP(s6 + 1, 1, 0, r1a, r1b, r2a, r2b);
    IMG_STEP(s6 + 2, 0, 1, r2a, r2b, r0a, r0b);
    IMG_STEP(s6 + 3, 1, 0, r0a, r0b, r1a, r1b);
    IMG_STEP(s6 + 4, 0, 1, r1a, r1b, r2a, r2b);
    IMG_STEP(s6 + 5, 1, 0, r2a, r2b, r0a, r0b);
  }
#undef IMG_LOAD
#undef IMG_WRITE
#undef IMG_MFMA
#undef IMG_STEP

  __bf16* P = partials + (size_t)zz * (512 * 512);
  const int rq = (lane >> 4) * 4;
#pragma unroll
  for (int i = 0; i < 4; ++i)
#pragma unroll
    for (int j = 0; j < 2; ++j)
#pragma unroll
      for (int r = 0; r < 4; ++r)
        P[(size_t)(m0 + wr + i * 16 + rq + r) * 512 + (n0 + wc + j * 16 + fr)] =
            (__bf16)acc[i][j][r];
}

// =====================================================================
// pool body (LDS-staged A rows, proven)
// =====================================================================
__device__ __forceinline__ void pool_body(
    int pbid, const float* __restrict__ qgrids, const int* __restrict__ lens,
    const __bf16* __restrict__ Wt, const float* __restrict__ bias,
    const float* __restrict__ g, const float* __restrict__ bt,
    __bf16* __restrict__ pooled, float (*red)[16][2], float (*Arows)[258]) {
  const int t = threadIdx.x, lane = t & 63, w = t >> 6;
  const int b = pbid >> 5;
  const int j0 = (pbid & 31) * 16;
  const int L = lens[b];
  int S = (L + 511) >> 9;
  if (S < 1) S = 1;
  const int new_len = (L + S - 1) / S;
  const float* qg_b = qgrids + (size_t)b * 4096 * 242;
  __bf16* pooled_b = pooled + (size_t)b * 512 * 512;

  const int fr = lane & 15;
  const int fq = lane >> 4;
  const int fkq = fq * 8;
  const int colbase = w * 64;

  float biasv[4], gv[4], btv[4];
#pragma unroll
  for (int nt = 0; nt < 4; ++nt) {
    const int col = colbase + nt * 16 + fr;
    biasv[nt] = bias[col];
    gv[nt] = g[col];
    btv[nt] = bt[col];
  }

  f32x4 pool[4];
#pragma unroll
  for (int nt = 0; nt < 4; ++nt) pool[nt] = f32x4{0.f, 0.f, 0.f, 0.f};

  {
    const int row = t >> 5, l32 = t & 31;
    if (l32 < 16) Arows[row][242 + l32] = 0.f;
  }

  for (int i = 0; i < S; ++i) {
    {
      const int row = t >> 5, l32 = t & 31;
      const int arow = (j0 + row) * S + i;
      const float* src = qg_b + (size_t)arow * 242;
#pragma unroll
      for (int c8 = 0; c8 < 4; ++c8) {
        const int c = (l32 + c8 * 32) * 2;
        if (c < 242) {
          f32x2 v = *reinterpret_cast<const f32x2*>(src + c);
          Arows[row][c] = v[0];
          Arows[row][c + 1] = v[1];
        }
      }
    }
    __syncthreads();
    f32x4 acc[4];
#pragma unroll
    for (int nt = 0; nt < 4; ++nt) acc[nt] = f32x4{0.f, 0.f, 0.f, 0.f};
#pragma unroll
    for (int ks = 0; ks < 8; ++ks) {
      bf16x8 af = cvt8(&Arows[fr][ks * 32 + fkq]);
      const __bf16* wt = Wt + ks * 32 + fkq;
#pragma unroll
      for (int nt = 0; nt < 4; ++nt) {
        bf16x8 bfv = *reinterpret_cast<const bf16x8*>(
            wt + (size_t)(colbase + nt * 16 + fr) * 256);
        acc[nt] = mfma16(af, bfv, acc[nt]);
      }
    }
    float s[4] = {0.f, 0.f, 0.f, 0.f}, sq[4] = {0.f, 0.f, 0.f, 0.f};
#pragma unroll
    for (int nt = 0; nt < 4; ++nt) {
#pragma unroll
      for (int r = 0; r < 4; ++r) {
        const float v = acc[nt][r] + biasv[nt];
        acc[nt][r] = v;
        s[r] += v;
        sq[r] += v * v;
      }
    }
#pragma unroll
    for (int off = 1; off < 16; off <<= 1) {
#pragma unroll
      for (int r = 0; r < 4; ++r) {
        s[r] += __shfl_xor(s[r], off, 64);
        sq[r] += __shfl_xor(sq[r], off, 64);
      }
    }
    if (fr == 0) {
#pragma unroll
      for (int r = 0; r < 4; ++r) {
        red[w][fq * 4 + r][0] = s[r];
        red[w][fq * 4 + r][1] = sq[r];
      }
    }
    __syncthreads();
    float mean[4], rsig[4];
#pragma unroll
    for (int r = 0; r < 4; ++r) {
      const int p = fq * 4 + r;
      float ss = 0.f, qq = 0.f;
#pragma unroll
      for (int ww = 0; ww < 8; ++ww) {
        ss += red[ww][p][0];
        qq += red[ww][p][1];
      }
      const float m = ss * (1.f / 512.f);
      mean[r] = m;
      rsig[r] = rsqrtf(qq * (1.f / 512.f) - m * m + 1e-5f);
    }
    __syncthreads();
#pragma unroll
    for (int r = 0; r < 4; ++r) {
      const int srow = (j0 + fq * 4 + r) * S + i;
      const bool ok = srow < L;
#pragma unroll
      for (int nt = 0; nt < 4; ++nt) {
        const float nv = (acc[nt][r] - mean[r]) * rsig[r] * gv[nt] + btv[nt];
        pool[nt][r] += ok ? nv : 0.f;
      }
    }
  }
  const float inv = 1.f / (float)S;
#pragma unroll
  for (int r = 0; r < 4; ++r) {
    const int j = j0 + fq * 4 + r;
    const bool ok = j < new_len;
#pragma unroll
    for (int nt = 0; nt < 4; ++nt)
      pooled_b[(size_t)j * 512 + colbase + nt * 16 + fr] =
          (__bf16)(ok ? pool[nt][r] * inv : 0.f);
  }
}

// kp body (512-thread mapping)
__device__ __forceinline__ void kp_body(
    int kpbid, const __bf16* __restrict__ A, const __bf16* __restrict__ Wt,
    const float* __restrict__ bias, float* __restrict__ C) {
  const int t = threadIdx.x, lane = t & 63, w = t >> 6;
  const int n0 = (kpbid & 31) * 16;
  const int m0 = (kpbid >> 5) * 128 + w * 16;
  const int fr = lane & 15, fq = lane >> 4;
  const __bf16* arow = A + (size_t)(m0 + fr) * 256 + fq * 8;
  const __bf16* brow = Wt + (size_t)(n0 + fr) * 256 + fq * 8;
  f32x4 acc = f32x4{0.f, 0.f, 0.f, 0.f};
#pragma unroll
  for (int ks = 0; ks < 8; ++ks) {
    bf16x8 a = *reinterpret_cast<const bf16x8*>(arow + ks * 32);
    bf16x8 b = *reinterpret_cast<const bf16x8*>(brow + ks * 32);
    acc = mfma16(a, b, acc);
  }
  const int col = n0 + fr;
  const float bv = bias[col];
  const int r0 = m0 + fq * 4;
#pragma unroll
  for (int r = 0; r < 4; ++r)
    C[(size_t)(r0 + r) * 512 + col] = fmaxf(acc[r] + bv, 0.f);
}

// =====================================================================
// Phase-1 fused: pool (bid<256) | img (bid<1040) | kp (else).
// NO min-waves launch bound: the (512,6) cap forced VGPR 40 and spilled
// the img pipeline (436us, WRITE 685MB -- round 18). VGPR 128 / 21%
// occupancy is the measured-optimal point (123us, total 204).
// =====================================================================
__global__ __launch_bounds__(512) void phase1_kernel(
    const float* __restrict__ images, const float* __restrict__ W_img,
    __bf16* __restrict__ partials, const float* __restrict__ qgrids,
    const int* __restrict__ lens, const __bf16* __restrict__ wtq,
    const float* __restrict__ b_qp, const float* __restrict__ g_qln,
    const float* __restrict__ bt_qln, __bf16* __restrict__ pooled,
    const __bf16* __restrict__ kpbf, const __bf16* __restrict__ wkp_t,
    const float* __restrict__ b_kp, float* __restrict__ kptmp) {
  __shared__ union {
    struct {
      __bf16 As[2][5120];
      __bf16 Bs[2][5120];
    } img;
    struct {
      float red[8][16][2];
      float Arows[16][258];
    } pool;
  } sm;
  const int bid = blockIdx.x;
  if (bid < 256) {
    pool_body(bid, qgrids, lens, wtq, b_qp, g_qln, bt_qln, pooled,
              sm.pool.red, sm.pool.Arows);
  } else if (bid < 1040) {
    img_body(bid - 256, images, W_img, partials, sm.img.As, sm.img.Bs);
  } else {
    kp_body(bid - 1040, kpbf, wkp_t, b_kp, kptmp);
  }
}

// =====================================================================
// reduce_ln: fusedbf[row, :512] = bf16( LN(kptmp[row])*g+bt + b_img
//                                       + sum_z partials[z][row] )
// =====================================================================
__global__ __launch_bounds__(256) void reduce_ln_kernel(
    const float* __restrict__ kptmp, const float* __restrict__ g,
    const float* __restrict__ bt, const __bf16* __restrict__ partials,
    const float* __restrict__ b_img, __bf16* __restrict__ fusedbf) {
  __shared__ float red[8];
  const int t = threadIdx.x;
  const int row = blockIdx.x;
  const size_t off = (size_t)row * 512;
  const float a = kptmp[off + t], b2 = kptmp[off + t + 256];
  float s = a + b2, sq = a * a + b2 * b2;
  blockRed2(s, sq, red);
  const float m = s * (1.f / 512.f);
  const float var = sq * (1.f / 512.f) - m * m;
  const float rs = rsqrtf(var + 1e-5f);
  float acc0 = (a - m) * rs * g[t] + bt[t] + b_img[t];
  float acc1 = (b2 - m) * rs * g[t + 256] + bt[t + 256] + b_img[t + 256];
#pragma unroll
  for (int z = 0; z < SPLITK; ++z) {
    acc0 += (float)partials[(size_t)z * 262144 + off + t];
    acc1 += (float)partials[(size_t)z * 262144 + off + t + 256];
  }
  __bf16* dst = fusedbf + (size_t)row * 1024;
  dst[t] = (__bf16)acc0;
  dst[t + 256] = (__bf16)acc1;
}

// =====================================================================
// prep3: wqp^T | wkp^T | kp cast (1536 blocks, 256 thr)
// =====================================================================
__global__ __launch_bounds__(256) void prep3_kernel(
    const float* __restrict__ W_qp, __bf16* __restrict__ wtq,
    const float* __restrict__ W_kp, __bf16* __restrict__ wkp_t,
    const float* __restrict__ kp, __bf16* __restrict__ kpbf) {
  const int bid = blockIdx.x;
  const int t = threadIdx.x;
  if (bid < 512) {
    wtq[(size_t)bid * 256 + t] =
        (t < 242) ? (__bf16)W_qp[(size_t)t * 512 + bid] : (__bf16)0.f;
  } else if (bid < 1024) {
    const int c = bid - 512;
    wkp_t[(size_t)c * 256 + t] =
        (t < 242) ? (__bf16)W_kp[(size_t)t * 512 + c] : (__bf16)0.f;
  } else {
    const int r = bid - 1024;
    kpbf[(size_t)r * 256 + t] =
        (t < 242) ? (__bf16)kp[(size_t)r * 242 + t] : (__bf16)0.f;
  }
}

// =====================================================================
// transpose body (LDS-tiled): W [NK][NC] f32 -> Wt [NC][NK]
// =====================================================================
__device__ __forceinline__ void wtrans_body(const float* __restrict__ W,
                                            __bf16* __restrict__ Wt, int NC,
                                            int NK, int bx, int by) {
  __shared__ float T[32][33];
  const int t = threadIdx.x;
  const int c0 = bx * 32;
  const int k0 = by * 32;
#pragma unroll
  for (int r = 0; r < 4; ++r) {
    const int idx = r * 256 + t;
    const int i = idx >> 5, j = idx & 31;
    const int c = c0 + j;
    T[i][j] = (c < NC) ? W[(size_t)(k0 + i) * NC + c] : 0.f;
  }
  __syncthreads();
#pragma unroll
  for (int r = 0; r < 4; ++r) {
    const int idx = r * 256 + t;
    const int i = idx >> 5, j = idx & 31;
    const int c = c0 + i;
    if (c < NC) Wt[(size_t)c * NK + k0 + j] = (__bf16)T[j][i];
  }
}

__global__ __launch_bounds__(256) void wtrans_kernel(
    const float* __restrict__ W, __bf16* __restrict__ Wt, int NC, int NK) {
  wtrans_body(W, Wt, NC, NK, blockIdx.x, blockIdx.y);
}

__global__ __launch_bounds__(256) void wtrans4_kernel(
    const float* __restrict__ W0, const float* __restrict__ W1,
    const float* __restrict__ W2, const float* __restrict__ W3,
    __bf16* __restrict__ T0, __bf16* __restrict__ T1,
    __bf16* __restrict__ T2, __bf16* __restrict__ T3) {
  const float* W = (blockIdx.z == 0) ? W0 : (blockIdx.z == 1) ? W1
                   : (blockIdx.z == 2) ? W2 : W3;
  __bf16* Wt = (blockIdx.z == 0) ? T0 : (blockIdx.z == 1) ? T1
               : (blockIdx.z == 2) ? T2 : T3;
  wtrans_body(W, Wt, 512, 512, blockIdx.x, blockIdx.y);
}

// =====================================================================
// Register GEMM, K=512: one 16x16 tile per wave, no LDS, no barriers.
// =====================================================================
template <typename OutT>
__global__ __launch_bounds__(256) void reg_gemm512_kernel(
    const __bf16* __restrict__ A, int lda, const __bf16* __restrict__ Wt,
    const float* __restrict__ bias, OutT* __restrict__ C, int ldc) {
  const int t = threadIdx.x, lane = t & 63, w = t >> 6;
  const int n0 = blockIdx.x * 16;
  const int m0 = blockIdx.y * 64 + w * 16;
  const int fr = lane & 15, fq = lane >> 4;
  const __bf16* arow = A + (size_t)(m0 + fr) * lda + fq * 8;
  const __bf16* brow = Wt + (size_t)(n0 + fr) * 512 + fq * 8;
  f32x4 acc = f32x4{0.f, 0.f, 0.f, 0.f};
#pragma unroll
  for (int ks = 0; ks < 16; ++ks) {
    bf16x8 a = *reinterpret_cast<const bf16x8*>(arow + ks * 32);
    bf16x8 b = *reinterpret_cast<const bf16x8*>(brow + ks * 32);
    acc = mfma16(a, b, acc);
  }
  const int col = n0 + fr;
  const float bv = bias[col];
  const int r0 = m0 + fq * 4;
#pragma unroll
  for (int r = 0; r < 4; ++r)
    C[(size_t)(r0 + r) * ldc + col] = (OutT)(acc[r] + bv);
}

// K+V in one launch (blockIdx.z picks weight/bias/output)
__global__ __launch_bounds__(256) void kv_reg_gemm_kernel(
    const __bf16* __restrict__ A, const __bf16* __restrict__ wk_t,
    const float* __restrict__ bk, const __bf16* __restrict__ wv_t,
    const float* __restrict__ bv, __bf16* __restrict__ kout,
    __bf16* __restrict__ vout) {
  const __bf16* Wt = blockIdx.z ? wv_t : wk_t;
  const float* bias = blockIdx.z ? bv : bk;
  __bf16* C = blockIdx.z ? vout : kout;
  const int t = threadIdx.x, lane = t & 63, w = t >> 6;
  const int n0 = blockIdx.x * 16;
  const int m0 = blockIdx.y * 64 + w * 16;
  const int fr = lane & 15, fq = lane >> 4;
  const __bf16* arow = A + (size_t)(m0 + fr) * 512 + fq * 8;
  const __bf16* brow = Wt + (size_t)(n0 + fr) * 512 + fq * 8;
  f32x4 acc = f32x4{0.f, 0.f, 0.f, 0.f};
#pragma unroll
  for (int ks = 0; ks < 16; ++ks) {
    bf16x8 a = *reinterpret_cast<const bf16x8*>(arow + ks * 32);
    bf16x8 b = *reinterpret_cast<const bf16x8*>(brow + ks * 32);
    acc = mfma16(a, b, acc);
  }
  const int col = n0 + fr;
  const float bvv = bias[col];
  const int r0 = m0 + fq * 4;
#pragma unroll
  for (int r = 0; r < 4; ++r)
    C[(size_t)(r0 + r) * 512 + col] = (__bf16)(acc[r] + bvv);
}

// CTC head register GEMM (K=1024)
__global__ __launch_bounds__(256) void ctc_gemm_kernel(
    const __bf16* __restrict__ A, const __bf16* __restrict__ Wt,
    const float* __restrict__ bias, float* __restrict__ out) {
  const int t = threadIdx.x, lane = t & 63, w = t >> 6;
  const int n0 = blockIdx.x * 16;
  const int m0 = blockIdx.y * 64 + w * 16;
  const int fr = lane & 15, fq = lane >> 4;
  const __bf16* arow = A + (size_t)(m0 + fr) * 1024 + fq * 8;
  const __bf16* brow = Wt + (size_t)(n0 + fr) * 1024 + fq * 8;
  f32x4 acc = f32x4{0.f, 0.f, 0.f, 0.f};
#pragma unroll
  for (int ks = 0; ks < 32; ++ks) {
    bf16x8 a = *reinterpret_cast<const bf16x8*>(arow + ks * 32);
    bf16x8 b = *reinterpret_cast<const bf16x8*>(brow + ks * 32);
    acc = mfma16(a, b, acc);
  }
  const int col = n0 + fr;
  const float bv = bias[col];
  const int r0 = m0 + fq * 4;
#pragma unroll
  for (int r = 0; r < 4; ++r)
    out[(size_t)(r0 + r) * 1296 + col] = acc[r] + bv;
}

// =====================================================================
// Fused attention (unchanged, proven)
// =====================================================================
__global__ __launch_bounds__(256) void attn_fused_kernel(
    const __bf16* __restrict__ q, const __bf16* __restrict__ k,
    const __bf16* __restrict__ v, const int* __restrict__ lens,
    __bf16* __restrict__ ctx) {
  __shared__ __bf16 Qs[64 * 72];
  __shared__ __bf16 Ps[64 * 520];
  __shared__ __bf16 KVs[64 * 520];
  const int t = threadIdx.x, lane = t & 63, w = t >> 6;
  const int bh = blockIdx.x, b = bh >> 3, h = bh & 7;
  const int L = lens[b];
  const int sdiv = (L + 511) >> 9;
  const int new_len = (L + sdiv - 1) / sdiv;
  const size_t qbase = (size_t)b * 64 * 512 + h * 64;
  const size_t kbase = (size_t)b * 512 * 512 + h * 64;
  const size_t vbase = kbase;
  const int fr = lane & 15, fkq = (lane >> 4) * 8;

#pragma unroll
  for (int rep = 0; rep < 4; ++rep) {
    const int gidx = rep * 256 + t;
    const int row = gidx >> 4, c = (gidx & 15) * 4;
    *reinterpret_cast<bf16x4*>(&Qs[row * 72 + c]) =
        *reinterpret_cast<const bf16x4*>(&q[qbase + (size_t)row * 512 + c]);
  }
  f32x4 acc[32];
#pragma unroll
  for (int nt = 0; nt < 32; ++nt) acc[nt] = f32x4{0.f, 0.f, 0.f, 0.f};
  for (int ks = 0; ks < 2; ++ks) {
    const int k0 = ks * 32;
#pragma unroll
    for (int rep = 0; rep < 16; ++rep) {
      const int gidx = rep * 256 + t;
      const int row = gidx >> 3, c = (gidx & 7) * 4;
      *reinterpret_cast<bf16x4*>(&KVs[row * 40 + c]) =
          *reinterpret_cast<const bf16x4*>(&k[kbase + (size_t)row * 512 + k0 + c]);
    }
    __syncthreads();
    const bf16x8 af =
        *reinterpret_cast<const bf16x8*>(&Qs[(w * 16 + fr) * 72 + k0 + fkq]);
#pragma unroll
    for (int nt = 0; nt < 32; ++nt) {
      bf16x8 bf = *reinterpret_cast<const bf16x8*>(&KVs[(nt * 16 + fr) * 40 + fkq]);
      acc[nt] = mfma16(af, bf, acc[nt]);
    }
    __syncthreads();
  }
  const float scale = 0.125f;
#pragma unroll
  for (int r = 0; r < 4; ++r) {
    float mx = -3.0e38f;
#pragma unroll
    for (int nt = 0; nt < 32; ++nt) {
      const int col = nt * 16 + fr;
      const float sv = acc[nt][r] * scale;
      if (col < new_len) mx = fmaxf(mx, sv);
    }
#pragma unroll
    for (int off = 1; off < 16; off <<= 1) mx = fmaxf(mx, __shfl_xor(mx, off, 64));
    float sum = 0.f;
#pragma unroll
    for (int nt = 0; nt < 32; ++nt) {
      const int col = nt * 16 + fr;
      const float e = (col < new_len) ? __expf(acc[nt][r] * scale - mx) : 0.f;
      acc[nt][r] = e;
      sum += e;
    }
#pragma unroll
    for (int off = 1; off < 16; off <<= 1) sum += __shfl_xor(sum, off, 64);
    const float inv = 1.f / sum;
    const int row = w * 16 + ((lane >> 4) << 2) + r;
#pragma unroll
    for (int nt = 0; nt < 32; ++nt)
      Ps[row * 520 + nt * 16 + fr] = (__bf16)(acc[nt][r] * inv);
  }
  __syncthreads();
  {
    const int d = t & 63;
    const int kc = (t >> 6) * 128;
    const int sw = (d & 7) << 3;
#pragma unroll
    for (int j8 = 0; j8 < 16; ++j8) {
      const int kv0 = kc + j8 * 8;
      bf16x8 tmp;
#pragma unroll
      for (int jj = 0; jj < 8; ++jj)
        tmp[jj] = v[vbase + (size_t)(kv0 + jj) * 512 + d];
      *reinterpret_cast<bf16x8*>(&KVs[d * 520 + (kv0 ^ sw)]) = tmp;
    }
  }
  __syncthreads();
  f32x4 acc2[4];
#pragma unroll
  for (int nt = 0; nt < 4; ++nt) acc2[nt] = f32x4{0.f, 0.f, 0.f, 0.f};
  const int swr = (fr & 7) << 3;
#pragma unroll
  for (int s = 0; s < 16; ++s) {
    const int k0 = s * 32;
    const bf16x8 af =
        *reinterpret_cast<const bf16x8*>(&Ps[(w * 16 + fr) * 520 + k0 + fkq]);
#pragma unroll
    for (int nt = 0; nt < 4; ++nt) {
      bf16x8 bf = *reinterpret_cast<const bf16x8*>(
          &KVs[(nt * 16 + fr) * 520 + ((k0 + fkq) ^ swr)]);
      acc2[nt] = mfma16(af, bf, acc2[nt]);
    }
  }
  const int rq = (lane >> 4) * 4;
  const size_t cbase = (size_t)b * 64 * 512 + h * 64;
#pragma unroll
  for (int nt = 0; nt < 4; ++nt)
#pragma unroll
    for (int r = 0; r < 4; ++r)
      ctx[cbase + (size_t)(w * 16 + rq + r) * 512 + nt * 16 + fr] =
          (__bf16)acc2[nt][r];
}

// LayerNorm over rows of 512, bf16 output into fusedbf[:, 512:1024]
__global__ __launch_bounds__(256) void ln_bf16_kernel(
    const float* __restrict__ x, const float* __restrict__ g,
    const float* __restrict__ bt, __bf16* __restrict__ ybf) {
  __shared__ float red[8];
  const int t = threadIdx.x;
  const size_t off = (size_t)blockIdx.x * 512;
  const float a = x[off + t], b2 = x[off + t + 256];
  float s = a + b2, sq = a * a + b2 * b2;
  blockRed2(s, sq, red);
  const float m = s * (1.f / 512.f);
  const float var = sq * (1.f / 512.f) - m * m;
  const float rs = rsqrtf(var + 1e-5f);
  __bf16* yrow = ybf + (size_t)blockIdx.x * 1024;
  yrow[t] = (__bf16)((a - m) * rs * g[t] + bt[t]);
  yrow[t + 256] = (__bf16)((b2 - m) * rs * g[t + 256] + bt[t + 256]);
}

// =====================================================================
// Workspace layout (round-16/17 proven):
//   ws+ 0.. 1    kptmp f32 (phase1 -> reduce_ln)
//   ws+ 1..1.5   qbuf bf16; ws+1.5..2 ctxbf bf16
//   ws+ 2.. 3    wtq 256KB (prep -> phase1) / ctxo f32 (wo -> ln)
//   ws+ 3.. 4    fusedbf (reduce_ln -> q/ctc; ln -> ctc)
//   ws+ 4.. 8    pooled bf16 (phase1 -> kv) [exclusive vs partials]
//   ws+ 8..32.5  partials (phase1 -> reduce_ln); after death:
//                kbuf 8..12, vbuf 12..16, wtc 16..18.6
//   ws+32.5..34.5 wq_t/wk_t/wv_t/wo_t
//   ws+34.5..34.75 kpbf; 34.75..35 wkp_t
// =====================================================================
extern "C" void kernel_launch(void* const* d_in, const int* in_sizes, int n_in,
                              void* d_out, int out_size, void* d_ws,
                              size_t ws_size, hipStream_t stream) {
  const float* images = (const float*)d_in[0];
  const float* qgrids = (const float*)d_in[1];
  const float* keypoints = (const float*)d_in[2];
  const int* qlens = (const int*)d_in[3];
  const float* W_img = (const float*)d_in[4];
  const float* b_img = (const float*)d_in[5];
  const float* W_kp = (const float*)d_in[6];
  const float* b_kp = (const float*)d_in[7];
  const float* g_kp = (const float*)d_in[8];
  const float* bt_kp = (const float*)d_in[9];
  const float* W_qp = (const float*)d_in[10];
  const float* b_qp = (const float*)d_in[11];
  const float* g_qln = (const float*)d_in[12];
  const float* bt_qln = (const float*)d_in[13];
  const float* Wq = (const float*)d_in[14];
  const float* bq = (const float*)d_in[15];
  const float* Wk = (const float*)d_in[16];
  const float* bk = (const float*)d_in[17];
  const float* Wv = (const float*)d_in[18];
  const float* bv = (const float*)d_in[19];
  const float* Wo = (const float*)d_in[20];
  const float* bo = (const float*)d_in[21];
  const float* g_attn = (const float*)d_in[22];
  const float* bt_attn = (const float*)d_in[23];
  const float* W_ctc = (const float*)d_in[24];
  const float* b_ctc = (const float*)d_in[25];
  float* out = (float*)d_out;

  const size_t MB = 1u << 20;
  const size_t KB = 1u << 10;
  if (ws_size < 35 * MB) return;
  char* ws = (char*)d_ws;
  float* kptmp = (float*)(ws);
  __bf16* qbuf = (__bf16*)(ws + 1 * MB);
  __bf16* ctxbf = (__bf16*)(ws + 1 * MB + 512 * KB);
  __bf16* wtq = (__bf16*)(ws + 2 * MB);
  float* ctxo = (float*)(ws + 2 * MB);
  __bf16* fusedbf = (__bf16*)(ws + 3 * MB);
  __bf16* pooled = (__bf16*)(ws + 4 * MB);
  __bf16* partials = (__bf16*)(ws + 8 * MB);
  __bf16* kbuf = (__bf16*)(ws + 8 * MB);    // after partials die
  __bf16* vbuf = (__bf16*)(ws + 12 * MB);   // after partials die
  __bf16* wtc = (__bf16*)(ws + 16 * MB);    // after partials die
  __bf16* wq_t = (__bf16*)(ws + 32 * MB + 512 * KB);
  __bf16* wk_t = (__bf16*)(ws + 33 * MB);
  __bf16* wv_t = (__bf16*)(ws + 33 * MB + 512 * KB);
  __bf16* wo_t = (__bf16*)(ws + 34 * MB);
  __bf16* kpbf = (__bf16*)(ws + 34 * MB + 512 * KB);
  __bf16* wkp_t = (__bf16*)(ws + 34 * MB + 768 * KB);

  // 0) prep: wqp^T + wkp^T + kp cast; qkvo transposes
  prep3_kernel<<<1536, 256, 0, stream>>>(W_qp, wtq, W_kp, wkp_t, keypoints,
                                         kpbf);
  wtrans4_kernel<<<dim3(16, 16, 4), 256, 0, stream>>>(Wq, Wk, Wv, Wo, wq_t,
                                                      wk_t, wv_t, wo_t);
  // 1) phase-1 fused: pool(256) | img(784) | kp(128)  [uncapped VGPR]
  phase1_kernel<<<1168, 512, 0, stream>>>(images, W_img, partials, qgrids,
                                          qlens, wtq, b_qp, g_qln, bt_qln,
                                          pooled, kpbf, wkp_t, b_kp, kptmp);
  // 2) reduce_ln: LN(kptmp) + b_img + sum(partials) -> fusedbf[:, :512]
  reduce_ln_kernel<<<512, 256, 0, stream>>>(kptmp, g_kp, bt_kp, partials,
                                            b_img, fusedbf);
  // 3) ctc weight transpose (partials dead -> wtc region free)
  wtrans_kernel<<<dim3(41, 32), 256, 0, stream>>>(W_ctc, wtc, 1296, 1024);
  // 4) k + v via register GEMM
  kv_reg_gemm_kernel<<<dim3(32, 64, 2), 256, 0, stream>>>(pooled, wk_t, bk,
                                                          wv_t, bv, kbuf, vbuf);
  // 5) q via register GEMM (A = fusedbf low-half, lda=1024)
  reg_gemm512_kernel<__bf16><<<dim3(32, 8), 256, 0, stream>>>(
      fusedbf, 1024, wq_t, bq, qbuf, 512);
  // 6) fused attention
  attn_fused_kernel<<<64, 256, 0, stream>>>(qbuf, kbuf, vbuf, qlens, ctxbf);
  // 7) ctx @ Wo + bo (f32), then LN -> fusedbf[:, 512:]
  reg_gemm512_kernel<float><<<dim3(32, 8), 256, 0, stream>>>(
      ctxbf, 512, wo_t, bo, ctxo, 512);
  ln_bf16_kernel<<<512, 256, 0, stream>>>(ctxo, g_attn, bt_attn, fusedbf + 512);
  // 8) out = fusedbf @ Wt_ctc^T + b_ctc
  ctc_gemm_kernel<<<dim3(81, 8), 256, 0, stream>>>(fusedbf, wtc, b_ctc, out);
}